// Round 1
// baseline (15037.956 us; speedup 1.0000x reference)
//
#include <hip/hip_runtime.h>

typedef _Float16 half_t;
typedef _Float16 half8 __attribute__((ext_vector_type(8)));
typedef float f32x4 __attribute__((ext_vector_type(4)));

#define DI __device__ __forceinline__

constexpr int Bsz = 256;   // batch
constexpr int Tsz = 128;   // seq len
constexpr int Fsz = 32;    // feature
constexpr int Hsz = 1024;  // hidden
constexpr int NG  = 4096;  // 4*H gate rows
constexpr int K1  = 1152;  // padded 1024+32 (pad zeroed)
constexpr int K2  = 2048;  // 1024+1024

// Gate permutation: tile nt (64 cols) holds all 4 gates for 16 hidden units.
// n' = nt*64 + g*16 + jo   <->   n = g*1024 + nt*16 + jo
DI int perm_to_orig(int np) {
    int nt = np >> 6, r = np & 63, g = r >> 4, jo = r & 15;
    return g * Hsz + nt * 16 + jo;
}

// ---------------- prep kernels (run every launch; deterministic) ----------------

// dst[n'][k] = k<KA ? srcA[n][k] : (k<KA+KB ? srcB[n][k-KA] : 0)
__global__ void pack_cat(half_t* __restrict__ dst, const float* __restrict__ srcA, int KA,
                         const float* __restrict__ srcB, int KB, int KP) {
    int k = blockIdx.x * 256 + threadIdx.x;
    int np = blockIdx.y;
    if (k >= KP) return;
    int n = perm_to_orig(np);
    float v = 0.f;
    if (k < KA) v = srcA[(size_t)n * KA + k];
    else if (k < KA + KB) v = srcB[(size_t)n * KB + (k - KA)];
    dst[(size_t)np * KP + k] = (half_t)v;
}

// Fill dst cols [1024,2048) with Wfold[n][j] = sum_f Wih0[n][f]*linW[f][j]
__global__ void pack_fold(half_t* __restrict__ dst, const float* __restrict__ Wih0,
                          const float* __restrict__ linW) {
    __shared__ float lw[32][128];
    __shared__ float wi[16][32];
    int nb = blockIdx.x * 16;
    int jb = blockIdx.y * 128;
    int t = threadIdx.x;
    for (int i = t; i < 32 * 128; i += 256) { int f = i >> 7, j = i & 127; lw[f][j] = linW[f * Hsz + jb + j]; }
    for (int i = t; i < 16 * 32; i += 256) { int r = i >> 5, f = i & 31; wi[r][f] = Wih0[perm_to_orig(nb + r) * 32 + f]; }
    __syncthreads();
    for (int i = t; i < 16 * 128; i += 256) {
        int r = i >> 7, j = i & 127;
        float s = 0.f;
#pragma unroll
        for (int f = 0; f < 32; ++f) s += wi[r][f] * lw[f][j];
        dst[(size_t)(nb + r) * K2 + 1024 + jb + j] = (half_t)s;
    }
}

// 5 permuted f32 bias vectors; slot 3 = dec_b0 + Wih0@lin_b (folded)
__global__ void pack_bias(float* __restrict__ b5, const float* eb0, const float* eb1,
                          const float* db0, const float* db1, const float* dWih0,
                          const float* linb) {
    int idx = blockIdx.x * 256 + threadIdx.x;
    if (idx >= 5 * NG) return;
    int which = idx >> 12, np = idx & (NG - 1);
    int n = perm_to_orig(np);
    float v;
    if (which == 0) v = eb0[n];
    else if (which == 1) v = eb1[n];
    else if (which == 2) v = db0[n];
    else if (which == 3) {
        v = db0[n];
        for (int f = 0; f < 32; ++f) v += dWih0[n * 32 + f] * linb[f];
    } else v = db1[n];
    b5[idx] = v;
}

// lin_W f32->f16 (unpermuted) + stage x_0 into bufA0 x-slot
__global__ void pack_small(half_t* __restrict__ Wlin, half_t* __restrict__ bufA0,
                           const float* __restrict__ linW, const float* __restrict__ inseq) {
    int idx = blockIdx.x * 256 + threadIdx.x;
    if (idx < 32 * Hsz) Wlin[idx] = (half_t)linW[idx];
    if (idx < Bsz * Fsz) {
        int b = idx >> 5, f = idx & 31;
        bufA0[(size_t)b * K1 + 1024 + f] = (half_t)inseq[(size_t)b * (Tsz * Fsz) + f];
    }
}

// ---------------- fused GEMM + LSTM-cell phase kernel ----------------
// C(256 x 4096) = A(256 x K) @ W(4096 x K)^T ; epilogue: gate activations,
// c update (f32, in-place), h -> up to 3 f16 destinations, optional x-copy.
// grid = 256 (4 mt x 64 nt), block = 256 (4 waves, 2x2), 64x64 tile.

#define MFMA(acc, a, b) acc = __builtin_amdgcn_mfma_f32_16x16x32_f16(a, b, acc, 0, 0, 0)

template <int K>
__launch_bounds__(256, 1) __global__
void lstm_phase(const half_t* __restrict__ A, const half_t* __restrict__ W,
                const float* __restrict__ bias, float* __restrict__ c,
                half_t* __restrict__ hd0, int hs0,
                half_t* __restrict__ hd1, int hs1,
                half_t* __restrict__ hd2, int hs2,
                const float* __restrict__ xsrc, half_t* __restrict__ xdst) {
    __shared__ float ldsg[64][65];
    int bid = blockIdx.x;
    // XCD-aware mapping: 4 mt-tiles sharing a weight panel land on one XCD
    int low3 = bid & 7, rest = bid >> 3;
    int mt = rest & 3, nt = ((rest >> 2) << 3) | low3;
    int tid = threadIdx.x;
    int lane = tid & 63, w = tid >> 6;
    int wm = w >> 1, wn = w & 1;
    int l15 = lane & 15, l4 = lane >> 4;

    const half_t* pa0 = A + (size_t)(mt * 64 + wm * 32 + l15) * K + l4 * 8;
    const half_t* pa1 = pa0 + (size_t)16 * K;
    const half_t* pw0 = W + (size_t)(nt * 64 + wn * 32 + l15) * K + l4 * 8;
    const half_t* pw1 = pw0 + (size_t)16 * K;

    f32x4 acc00 = {}, acc01 = {}, acc10 = {}, acc11 = {};
    constexpr int CH = K / 64;  // 18 or 32 (even)

    half8 a00a, a01a, a10a, a11a, w00a, w01a, w10a, w11a;
    half8 a00b, a01b, a10b, a11b, w00b, w01b, w10b, w11b;

#define LD(p, off) (*(const half8*)((p) + (off)))
#define PRE(sfx, cc)                                                    \
    {                                                                   \
        a00##sfx = LD(pa0, (cc) * 64);      a01##sfx = LD(pa0, (cc) * 64 + 32); \
        a10##sfx = LD(pa1, (cc) * 64);      a11##sfx = LD(pa1, (cc) * 64 + 32); \
        w00##sfx = LD(pw0, (cc) * 64);      w01##sfx = LD(pw0, (cc) * 64 + 32); \
        w10##sfx = LD(pw1, (cc) * 64);      w11##sfx = LD(pw1, (cc) * 64 + 32); \
    }
#define CMP(sfx)                                   \
    {                                              \
        MFMA(acc00, a00##sfx, w00##sfx);           \
        MFMA(acc01, a00##sfx, w10##sfx);           \
        MFMA(acc10, a10##sfx, w00##sfx);           \
        MFMA(acc11, a10##sfx, w10##sfx);           \
        MFMA(acc00, a01##sfx, w01##sfx);           \
        MFMA(acc01, a01##sfx, w11##sfx);           \
        MFMA(acc10, a11##sfx, w01##sfx);           \
        MFMA(acc11, a11##sfx, w11##sfx);           \
    }

    PRE(a, 0);
    int cc = 0;
    for (; cc < CH - 2; cc += 2) {
        PRE(b, cc + 1);
        CMP(a);
        PRE(a, cc + 2);
        CMP(b);
    }
    PRE(b, CH - 1);
    CMP(a);
    CMP(b);
#undef LD
#undef PRE
#undef CMP

    // scatter gate values to LDS (C layout: col = lane&15, row = (lane>>4)*4+reg)
    int bl = wm * 32, nl = wn * 32;
#pragma unroll
    for (int r = 0; r < 4; ++r) {
        ldsg[bl + l4 * 4 + r][nl + l15] = acc00[r];
        ldsg[bl + l4 * 4 + r][nl + 16 + l15] = acc01[r];
        ldsg[bl + 16 + l4 * 4 + r][nl + l15] = acc10[r];
        ldsg[bl + 16 + l4 * 4 + r][nl + 16 + l15] = acc11[r];
    }
    __syncthreads();

    // LSTM cell update: thread -> (4 batch rows) x 1 hidden unit
    int jo = tid & 15;
    int b0_ = (tid >> 4) * 4;
    const float* bb = bias + nt * 64;
    float bi = bb[jo], bf = bb[16 + jo], bg = bb[32 + jo], bo = bb[48 + jo];
    int jg = nt * 16 + jo;
#pragma unroll
    for (int u = 0; u < 4; ++u) {
        int bl_ = b0_ + u;
        int bglob = mt * 64 + bl_;
        float vi = ldsg[bl_][jo] + bi;
        float vf = ldsg[bl_][16 + jo] + bf;
        float vg = ldsg[bl_][32 + jo] + bg;
        float vo = ldsg[bl_][48 + jo] + bo;
        float si = 1.f / (1.f + __expf(-vi));
        float sf = 1.f / (1.f + __expf(-vf));
        float so = 1.f / (1.f + __expf(-vo));
        float tg = 1.f - 2.f / (__expf(2.f * vg) + 1.f);
        size_t ci = (size_t)bglob * Hsz + jg;
        float cn = sf * c[ci] + si * tg;
        c[ci] = cn;
        float th = 1.f - 2.f / (__expf(2.f * cn) + 1.f);
        half_t hh = (half_t)(so * th);
        hd0[(size_t)bglob * hs0 + jg] = hh;
        if (hd1) hd1[(size_t)bglob * hs1 + jg] = hh;
        if (hd2) hd2[(size_t)bglob * hs2 + jg] = hh;
    }

    // stage next encoder input x_{t+1} (f32 -> f16), 4 WGs only
    if (xsrc && nt == 0) {
        for (int i = tid; i < 64 * 32; i += 256) {
            int bl_ = i >> 5, f = i & 31;
            int bglob = mt * 64 + bl_;
            xdst[(size_t)bglob * K1 + f] = (half_t)xsrc[(size_t)bglob * (Tsz * Fsz) + f];
        }
    }
}

// ---------------- final projection: out[b][t][f] = H1hist[t][b][:] . lin_W[f][:] + lin_b[f]
__launch_bounds__(256, 1) __global__
void lin_out(const half_t* __restrict__ H1, const half_t* __restrict__ Wl,
             const float* __restrict__ lb, float* __restrict__ out) {
    int w = threadIdx.x >> 6, lane = threadIdx.x & 63;
    int l15 = lane & 15, l4 = lane >> 4;
    int row0 = (blockIdx.x * 4 + w) * 16;  // flat row = t*256 + b
    const half_t* pa = H1 + (size_t)(row0 + l15) * Hsz + l4 * 8;
    const half_t* pb0 = Wl + (size_t)l15 * Hsz + l4 * 8;
    const half_t* pb1 = Wl + (size_t)(16 + l15) * Hsz + l4 * 8;
    f32x4 ac0 = {}, ac1 = {};
    for (int k = 0; k < Hsz; k += 32) {
        half8 a = *(const half8*)(pa + k);
        half8 b0 = *(const half8*)(pb0 + k);
        half8 b1 = *(const half8*)(pb1 + k);
        MFMA(ac0, a, b0);
        MFMA(ac1, a, b1);
    }
#pragma unroll
    for (int r = 0; r < 4; ++r) {
        int row = row0 + l4 * 4 + r;
        int t = row >> 8, b = row & 255;
        size_t o = (size_t)b * (Tsz * Fsz) + t * Fsz;
        out[o + l15] = ac0[r] + lb[l15];
        out[o + 16 + l15] = ac1[r] + lb[16 + l15];
    }
}

// ---------------- host ----------------

extern "C" void kernel_launch(void* const* d_in, const int* in_sizes, int n_in,
                              void* d_out, int out_size, void* d_ws, size_t ws_size,
                              hipStream_t stream) {
    (void)in_sizes; (void)n_in;
    const float* in_seq = (const float*)d_in[0];
    const float* eWih0 = (const float*)d_in[1];
    const float* eWhh0 = (const float*)d_in[2];
    const float* eb0 = (const float*)d_in[3];
    const float* eWih1 = (const float*)d_in[4];
    const float* eWhh1 = (const float*)d_in[5];
    const float* eb1 = (const float*)d_in[6];
    const float* dWih0 = (const float*)d_in[7];
    const float* dWhh0 = (const float*)d_in[8];
    const float* db0 = (const float*)d_in[9];
    const float* dWih1 = (const float*)d_in[10];
    const float* dWhh1 = (const float*)d_in[11];
    const float* db1 = (const float*)d_in[12];
    const float* linW = (const float*)d_in[13];
    const float* linb = (const float*)d_in[14];
    float* out = (float*)d_out;

    char* base = (char*)d_ws;
    size_t off = 0;
    auto alloc = [&](size_t bytes) {
        char* r = base + off;
        off = (off + bytes + 255) & ~(size_t)255;
        return r;
    };
    half_t* Wenc1 = (half_t*)alloc((size_t)NG * K1 * 2);
    half_t* Wenc2 = (half_t*)alloc((size_t)NG * K2 * 2);
    half_t* Wdec1a = (half_t*)alloc((size_t)NG * K1 * 2);
    half_t* Wdec1b = (half_t*)alloc((size_t)NG * K2 * 2);
    half_t* Wdec2 = (half_t*)alloc((size_t)NG * K2 * 2);
    half_t* Wlin = (half_t*)alloc((size_t)32 * Hsz * 2);
    float* bias5 = (float*)alloc((size_t)5 * NG * 4);
    float* c0 = (float*)alloc((size_t)Bsz * Hsz * 4);
    float* c1 = (float*)alloc((size_t)Bsz * Hsz * 4);
    half_t* bufA0 = (half_t*)alloc((size_t)Bsz * K1 * 2);
    half_t* bufA1 = (half_t*)alloc((size_t)Bsz * K1 * 2);
    half_t* bufD0 = (half_t*)alloc((size_t)Bsz * K2 * 2);
    half_t* bufD1 = (half_t*)alloc((size_t)Bsz * K2 * 2);
    half_t* bufB0 = (half_t*)alloc((size_t)Bsz * K2 * 2);
    half_t* bufB1 = (half_t*)alloc((size_t)Bsz * K2 * 2);
    half_t* H1hist = (half_t*)alloc((size_t)Tsz * Bsz * Hsz * 2);

    if (off > ws_size) {  // clean failure signature: all-zero output
        hipMemsetAsync(d_out, 0, (size_t)out_size * 4, stream);
        return;
    }

    half_t* bufA[2] = {bufA0, bufA1};
    half_t* bufD[2] = {bufD0, bufD1};
    half_t* bufB[2] = {bufB0, bufB1};
    float* be1 = bias5;
    float* be2 = bias5 + NG;
    float* bd1a = bias5 + 2 * NG;
    float* bd1b = bias5 + 3 * NG;
    float* bd2 = bias5 + 4 * NG;

    // ---- prep ----
    hipMemsetAsync(c0, 0, (size_t)Bsz * Hsz * 4, stream);
    hipMemsetAsync(c1, 0, (size_t)Bsz * Hsz * 4, stream);
    hipMemsetAsync(bufA0, 0, (size_t)Bsz * K1 * 2, stream);
    hipMemsetAsync(bufA1, 0, (size_t)Bsz * K1 * 2, stream);
    hipMemsetAsync(bufB0, 0, (size_t)Bsz * K2 * 2, stream);

    dim3 g1((K1 + 255) / 256, NG), g2((K2 + 255) / 256, NG);
    pack_cat<<<g1, 256, 0, stream>>>(Wenc1, eWhh0, 1024, eWih0, 32, K1);
    pack_cat<<<g2, 256, 0, stream>>>(Wenc2, eWih1, 1024, eWhh1, 1024, K2);
    pack_cat<<<g1, 256, 0, stream>>>(Wdec1a, dWhh0, 1024, dWih0, 32, K1);
    pack_cat<<<g2, 256, 0, stream>>>(Wdec1b, dWhh0, 1024, nullptr, 0, K2);
    pack_fold<<<dim3(NG / 16, Hsz / 128), 256, 0, stream>>>(Wdec1b, dWih0, linW);
    pack_cat<<<g2, 256, 0, stream>>>(Wdec2, dWih1, 1024, dWhh1, 1024, K2);
    pack_bias<<<(5 * NG + 255) / 256, 256, 0, stream>>>(bias5, eb0, eb1, db0, db1, dWih0, linb);
    pack_small<<<128, 256, 0, stream>>>(Wlin, bufA0, linW, in_seq);

    // ---- encoder ----
    for (int t = 0; t < Tsz; ++t) {
        int pp = t & 1;
        lstm_phase<K1><<<256, 256, 0, stream>>>(
            bufA[pp], Wenc1, be1, c0,
            bufB[pp], K2, bufA[1 - pp], K1, nullptr, 0,
            nullptr, nullptr);
        int tsel = (t + 1 < Tsz) ? t + 1 : Tsz - 1;
        lstm_phase<K2><<<256, 256, 0, stream>>>(
            bufB[pp], Wenc2, be2, c1,
            bufB[1 - pp] + 1024, K2, nullptr, 0, nullptr, 0,
            in_seq + (size_t)tsel * Fsz, bufA[1 - pp] + 1024);
    }

    // ---- decoder ----
    // t = 0: x = input_seq[:, T-1, :] (staged in bufA[0] by enc P2 @ t=127)
    lstm_phase<K1><<<256, 256, 0, stream>>>(
        bufA[0], Wdec1a, bd1a, c0,
        bufB[0], K2, bufD[1], K2, nullptr, 0,
        nullptr, nullptr);
    lstm_phase<K2><<<256, 256, 0, stream>>>(
        bufB[0], Wdec2, bd2, c1,
        bufB[1] + 1024, K2, bufD[1] + 1024, K2, H1hist, Hsz,
        nullptr, nullptr);
    for (int t = 1; t < Tsz; ++t) {
        int q = t & 1;
        lstm_phase<K2><<<256, 256, 0, stream>>>(
            bufD[q], Wdec1b, bd1b, c0,
            bufB[q], K2, bufD[1 - q], K2, nullptr, 0,
            nullptr, nullptr);
        lstm_phase<K2><<<256, 256, 0, stream>>>(
            bufB[q], Wdec2, bd2, c1,
            bufB[1 - q] + 1024, K2, bufD[1 - q] + 1024, K2, H1hist + (size_t)t * Bsz * Hsz, Hsz,
            nullptr, nullptr);
    }

    lin_out<<<512, 256, 0, stream>>>(H1hist, Wlin, linb, out);
}

// Round 2
// 6621.700 us; speedup vs baseline: 2.2710x; 2.2710x over previous
//
#include <hip/hip_runtime.h>

typedef _Float16 half_t;
typedef _Float16 half8 __attribute__((ext_vector_type(8)));
typedef _Float16 half4v __attribute__((ext_vector_type(4)));
typedef float f32x4 __attribute__((ext_vector_type(4)));

#define DI __device__ __forceinline__

constexpr int Bsz = 256;   // batch
constexpr int Tsz = 128;   // seq len
constexpr int Fsz = 32;    // feature
constexpr int Hsz = 1024;  // hidden
constexpr int NG  = 4096;  // 4*H gate rows
constexpr int K1  = 1152;  // padded 1024+32 (pad zeroed)
constexpr int K2  = 2048;  // 1024+1024

// Gate permutation: tile nt (64 gate-rows) holds all 4 gates for 16 hidden units.
// n' = nt*64 + g*16 + jo   <->   n = g*1024 + nt*16 + jo
DI int perm_to_orig(int np) {
    int nt = np >> 6, r = np & 63, g = r >> 4, jo = r & 15;
    return g * Hsz + nt * 16 + jo;
}

// ---- MFMA fragment-packed layouts (lane-contiguous, 1KB per wave-load) ----
// elem(idx, k) lives at ((kc*NI + idx>>4)*64 + l4*16 + (idx&15))*8 + (k&7)
// where kc = k>>5, l4 = (k>>3)&3.  W: NI = NG/16 = 256. A: NI = Bsz/16 = 16.
DI size_t wfrag(int np, int k) {
    return ((size_t)((k >> 5) * 256 + (np >> 4)) * 64 + ((k >> 3) & 3) * 16 + (np & 15)) * 8 + (k & 7);
}
DI size_t afrag(int b, int k) {
    return ((size_t)((k >> 5) * 16 + (b >> 4)) * 64 + ((k >> 3) & 3) * 16 + (b & 15)) * 8 + (k & 7);
}

// ---------------- prep kernels ----------------

// dst frag-packed: dst(np,k) = k<KA ? srcA[n][k] : (k<KA+KB ? srcB[n][k-KA] : 0)
// block = 64 np-lanes x 4 k-groups; grid (KP/32, NG/64)
__global__ void pack_cat(half_t* __restrict__ dst, const float* __restrict__ srcA, int KA,
                         const float* __restrict__ srcB, int KB, int KP) {
    int tid = threadIdx.x;
    int np = blockIdx.y * 64 + (tid & 63);
    int k0 = (blockIdx.x * 4 + (tid >> 6)) * 8;
    if (k0 >= KP) return;
    int n = perm_to_orig(np);
    half8 v;
#pragma unroll
    for (int j = 0; j < 8; ++j) {
        int k = k0 + j;
        float f = 0.f;
        if (k < KA) f = srcA[(size_t)n * KA + k];
        else if (k < KA + KB) f = srcB[(size_t)n * KB + (k - KA)];
        v[j] = (half_t)f;
    }
    *(half8*)(dst + wfrag(np, k0)) = v;
}

// Fill dst cols [1024,2048) with Wfold[n][h] = sum_f Wih0[n][f]*linW[f][h]
// block = 16 r x 16 j-groups(8); grid (NG/16, 1024/128)
__global__ void pack_fold(half_t* __restrict__ dst, const float* __restrict__ Wih0,
                          const float* __restrict__ linW) {
    __shared__ float lw[32][128];
    __shared__ float wi[16][32];
    int nb = blockIdx.x * 16;
    int jb = blockIdx.y * 128;
    int t = threadIdx.x;
    for (int i = t; i < 32 * 128; i += 256) { int f = i >> 7, j = i & 127; lw[f][j] = linW[f * Hsz + jb + j]; }
    for (int i = t; i < 16 * 32; i += 256) { int r = i >> 5, f = i & 31; wi[r][f] = Wih0[perm_to_orig(nb + r) * 32 + f]; }
    __syncthreads();
    int r = t >> 4, j0 = (t & 15) * 8;
    half8 v;
#pragma unroll
    for (int jj = 0; jj < 8; ++jj) {
        float s = 0.f;
#pragma unroll
        for (int f = 0; f < 32; ++f) s += wi[r][f] * lw[f][j0 + jj];
        v[jj] = (half_t)s;
    }
    *(half8*)(dst + wfrag(nb + r, 1024 + jb + j0)) = v;
}

// 5 permuted f32 bias vectors; slot 3 = dec_b0 + Wih0@lin_b (folded)
__global__ void pack_bias(float* __restrict__ b5, const float* eb0, const float* eb1,
                          const float* db0, const float* db1, const float* dWih0,
                          const float* linb) {
    int idx = blockIdx.x * 256 + threadIdx.x;
    if (idx >= 5 * NG) return;
    int which = idx >> 12, np = idx & (NG - 1);
    int n = perm_to_orig(np);
    float v;
    if (which == 0) v = eb0[n];
    else if (which == 1) v = eb1[n];
    else if (which == 2) v = db0[n];
    else if (which == 3) {
        v = db0[n];
        for (int f = 0; f < 32; ++f) v += dWih0[n * 32 + f] * linb[f];
    } else v = db1[n];
    b5[idx] = v;
}

// lin_W f32->f16 (row-major) + stage x_0 into bufA0 frag slot (cols 1024..1056)
__global__ void pack_small(half_t* __restrict__ Wlin, half_t* __restrict__ bufA0,
                           const float* __restrict__ linW, const float* __restrict__ inseq) {
    int idx = blockIdx.x * 256 + threadIdx.x;
    if (idx < 32 * Hsz) Wlin[idx] = (half_t)linW[idx];
    if (idx < Bsz * 4) {
        int b = idx >> 2, fg = idx & 3;
        half8 v;
#pragma unroll
        for (int j = 0; j < 8; ++j) v[j] = (half_t)inseq[(size_t)b * (Tsz * Fsz) + fg * 8 + j];
        *(half8*)(bufA0 + afrag(b, 1024 + fg * 8)) = v;
    }
}

// ---------------- fused GEMM + LSTM-cell phase kernel ----------------
// C(256 x 4096) = A(256 x K) @ W(4096 x K)^T, operands frag-packed.
// grid = 256 (4 mt x 64 nt), block = 256 = 4 waves. Waves SPLIT K (no operand
// duplication: each byte enters the CU once); partial f32 accs reduced via LDS,
// then fused LSTM epilogue: gates -> c update (f32) -> h to up to 3 frag dests.

template <int K>
__launch_bounds__(256, 1) __global__
void lstm_phase(const half_t* __restrict__ A, const half_t* __restrict__ W,
                const float* __restrict__ bias, float* __restrict__ c,
                half_t* __restrict__ hd0, int cb0,
                half_t* __restrict__ hd1, int cb1,
                half_t* __restrict__ hd2, int cb2,
                const float* __restrict__ xsrc, half_t* __restrict__ xdst) {
    constexpr int CHW = (K / 32) / 4;  // k-chunks per wave: 9 (K1) or 16 (K2)
    __shared__ float red[4][64][68];   // 69.6 KB; stride 68 -> ~2-way on writes
    int bid = blockIdx.x;
    // XCD swizzle: 4 mt-tiles sharing a weight panel land on one XCD (bid%8 fixed)
    int low3 = bid & 7, rest = bid >> 3;
    int mt = rest & 3, nt = ((rest >> 2) << 3) | low3;
    int tid = threadIdx.x, lane = tid & 63, w = tid >> 6;

    const half_t* pa = A + ((size_t)((w * CHW) * 16 + mt * 4) * 64 + lane) * 8;
    const half_t* pw = W + ((size_t)((w * CHW) * 256 + nt * 4) * 64 + lane) * 8;

    f32x4 acc[4][4] = {};
    half8 bA[3][4], bW[3][4];  // 3-stage prefetch; all indices static after unroll

#define LOADS(st, kk)                                                              \
    {                                                                              \
        _Pragma("unroll") for (int mi = 0; mi < 4; ++mi)                           \
            bA[st][mi] = *(const half8*)(pa + (size_t)(kk) * 8192 + mi * 512);     \
        _Pragma("unroll") for (int ni = 0; ni < 4; ++ni)                           \
            bW[st][ni] = *(const half8*)(pw + (size_t)(kk) * 131072 + ni * 512);   \
    }

    LOADS(0, 0)
    LOADS(1, 1)
#pragma unroll
    for (int kk = 0; kk < CHW; ++kk) {
        if (kk + 2 < CHW) LOADS((kk + 2) % 3, kk + 2)
        const int st = kk % 3;
#pragma unroll
        for (int mi = 0; mi < 4; ++mi)
#pragma unroll
            for (int ni = 0; ni < 4; ++ni)
                acc[mi][ni] = __builtin_amdgcn_mfma_f32_16x16x32_f16(bA[st][mi], bW[st][ni], acc[mi][ni], 0, 0, 0);
    }
#undef LOADS

    // cross-wave K reduction via LDS
    int l15 = lane & 15, l4 = lane >> 4;
#pragma unroll
    for (int mi = 0; mi < 4; ++mi)
#pragma unroll
        for (int ni = 0; ni < 4; ++ni)
#pragma unroll
            for (int r = 0; r < 4; ++r)
                red[w][mi * 16 + l4 * 4 + r][ni * 16 + l15] = acc[mi][ni][r];
    __syncthreads();

    // epilogue: thread -> (1 row, 4 hidden units)
    int row = tid >> 2, q = tid & 3, jo0 = q * 4;
    f32x4 g0 = {}, g1 = {}, g2 = {}, g3 = {};
#pragma unroll
    for (int ww = 0; ww < 4; ++ww) {
        g0 += *(const f32x4*)&red[ww][row][jo0];
        g1 += *(const f32x4*)&red[ww][row][16 + jo0];
        g2 += *(const f32x4*)&red[ww][row][32 + jo0];
        g3 += *(const f32x4*)&red[ww][row][48 + jo0];
    }
    const float* bb = bias + nt * 64;
    g0 += *(const f32x4*)(bb + jo0);
    g1 += *(const f32x4*)(bb + 16 + jo0);
    g2 += *(const f32x4*)(bb + 32 + jo0);
    g3 += *(const f32x4*)(bb + 48 + jo0);

    int bglob = mt * 64 + row;
    int jg0 = nt * 16 + jo0;
    float* cp = c + (size_t)bglob * Hsz + jg0;
    f32x4 cold = *(const f32x4*)cp;
    f32x4 cnew;
    half4v hv;
#pragma unroll
    for (int e = 0; e < 4; ++e) {
        float si = 1.f / (1.f + __expf(-g0[e]));
        float sf = 1.f / (1.f + __expf(-g1[e]));
        float tg = 1.f - 2.f / (__expf(2.f * g2[e]) + 1.f);
        float so = 1.f / (1.f + __expf(-g3[e]));
        float cn = sf * cold[e] + si * tg;
        cnew[e] = cn;
        float th = 1.f - 2.f / (__expf(2.f * cn) + 1.f);
        hv[e] = (half_t)(so * th);
    }
    *(f32x4*)cp = cnew;

    {
        int col = cb0 + jg0;
        *(half4v*)(hd0 + ((size_t)((col >> 5) * 16 + (bglob >> 4)) * 64 + ((col >> 3) & 3) * 16 + (bglob & 15)) * 8 + (col & 7)) = hv;
    }
    if (hd1) {
        int col = cb1 + jg0;
        *(half4v*)(hd1 + ((size_t)((col >> 5) * 16 + (bglob >> 4)) * 64 + ((col >> 3) & 3) * 16 + (bglob & 15)) * 8 + (col & 7)) = hv;
    }
    if (hd2) {
        int col = cb2 + jg0;
        *(half4v*)(hd2 + ((size_t)((col >> 5) * 16 + (bglob >> 4)) * 64 + ((col >> 3) & 3) * 16 + (bglob & 15)) * 8 + (col & 7)) = hv;
    }

    // stage next encoder input x (f32 -> f16 frag cols 1024..1056); nt==0 WGs only
    if (xsrc && nt == 0) {
        int f0 = q * 8;
        const float* xs = xsrc + (size_t)bglob * (Tsz * Fsz) + f0;
        half8 v;
#pragma unroll
        for (int j = 0; j < 8; ++j) v[j] = (half_t)xs[j];
        *(half8*)(xdst + afrag(bglob, 1024 + f0)) = v;
    }
}

// ---------------- final projection: out[b][t][f] = H1hist[t](frag) . lin_W[f][:] + lin_b
// grid 512, 4 waves each; wave handles one 16-row tile (rowt = t*16 + mi)
__launch_bounds__(256, 1) __global__
void lin_out(const half_t* __restrict__ H1, const half_t* __restrict__ Wl,
             const float* __restrict__ lb, float* __restrict__ out) {
    int w = threadIdx.x >> 6, lane = threadIdx.x & 63;
    int l15 = lane & 15, l4 = lane >> 4;
    int rowt = blockIdx.x * 4 + w;
    int t = rowt >> 4, mi = rowt & 15;
    const half_t* pa = H1 + (size_t)t * (Bsz * Hsz);
    const half_t* pb0 = Wl + (size_t)l15 * Hsz + l4 * 8;
    const half_t* pb1 = Wl + (size_t)(16 + l15) * Hsz + l4 * 8;
    f32x4 ac0 = {}, ac1 = {};
#pragma unroll 4
    for (int kc = 0; kc < 32; ++kc) {
        half8 a = *(const half8*)(pa + ((size_t)(kc * 16 + mi) * 64 + lane) * 8);
        half8 b0 = *(const half8*)(pb0 + kc * 32);
        half8 b1 = *(const half8*)(pb1 + kc * 32);
        ac0 = __builtin_amdgcn_mfma_f32_16x16x32_f16(a, b0, ac0, 0, 0, 0);
        ac1 = __builtin_amdgcn_mfma_f32_16x16x32_f16(a, b1, ac1, 0, 0, 0);
    }
#pragma unroll
    for (int r = 0; r < 4; ++r) {
        int row = rowt * 16 + l4 * 4 + r;  // flat = t*256 + b
        int b = row & 255;
        size_t o = (size_t)b * (Tsz * Fsz) + t * Fsz;
        out[o + l15] = ac0[r] + lb[l15];
        out[o + 16 + l15] = ac1[r] + lb[16 + l15];
    }
}

// ---------------- host ----------------

extern "C" void kernel_launch(void* const* d_in, const int* in_sizes, int n_in,
                              void* d_out, int out_size, void* d_ws, size_t ws_size,
                              hipStream_t stream) {
    (void)in_sizes; (void)n_in;
    const float* in_seq = (const float*)d_in[0];
    const float* eWih0 = (const float*)d_in[1];
    const float* eWhh0 = (const float*)d_in[2];
    const float* eb0 = (const float*)d_in[3];
    const float* eWih1 = (const float*)d_in[4];
    const float* eWhh1 = (const float*)d_in[5];
    const float* eb1 = (const float*)d_in[6];
    const float* dWih0 = (const float*)d_in[7];
    const float* dWhh0 = (const float*)d_in[8];
    const float* db0 = (const float*)d_in[9];
    const float* dWih1 = (const float*)d_in[10];
    const float* dWhh1 = (const float*)d_in[11];
    const float* db1 = (const float*)d_in[12];
    const float* linW = (const float*)d_in[13];
    const float* linb = (const float*)d_in[14];
    float* out = (float*)d_out;

    char* base = (char*)d_ws;
    size_t off = 0;
    auto alloc = [&](size_t bytes) {
        char* r = base + off;
        off = (off + bytes + 255) & ~(size_t)255;
        return r;
    };
    half_t* Wenc1 = (half_t*)alloc((size_t)NG * K1 * 2);
    half_t* Wenc2 = (half_t*)alloc((size_t)NG * K2 * 2);
    half_t* Wdec1a = (half_t*)alloc((size_t)NG * K1 * 2);
    half_t* Wdec1b = (half_t*)alloc((size_t)NG * K2 * 2);
    half_t* Wdec2 = (half_t*)alloc((size_t)NG * K2 * 2);
    half_t* Wlin = (half_t*)alloc((size_t)32 * Hsz * 2);
    float* bias5 = (float*)alloc((size_t)5 * NG * 4);
    float* c0 = (float*)alloc((size_t)Bsz * Hsz * 4);
    float* c1 = (float*)alloc((size_t)Bsz * Hsz * 4);
    half_t* bufA0 = (half_t*)alloc((size_t)Bsz * K1 * 2);
    half_t* bufA1 = (half_t*)alloc((size_t)Bsz * K1 * 2);
    half_t* bufD0 = (half_t*)alloc((size_t)Bsz * K2 * 2);
    half_t* bufD1 = (half_t*)alloc((size_t)Bsz * K2 * 2);
    half_t* bufB0 = (half_t*)alloc((size_t)Bsz * K2 * 2);
    half_t* bufB1 = (half_t*)alloc((size_t)Bsz * K2 * 2);
    half_t* H1hist = (half_t*)alloc((size_t)Tsz * Bsz * Hsz * 2);

    if (off > ws_size) {  // clean failure signature: all-zero output
        hipMemsetAsync(d_out, 0, (size_t)out_size * 4, stream);
        return;
    }

    half_t* bufA[2] = {bufA0, bufA1};
    half_t* bufD[2] = {bufD0, bufD1};
    half_t* bufB[2] = {bufB0, bufB1};
    float* be1 = bias5;
    float* be2 = bias5 + NG;
    float* bd1a = bias5 + 2 * NG;
    float* bd1b = bias5 + 3 * NG;
    float* bd2 = bias5 + 4 * NG;

    // ---- prep ----
    hipMemsetAsync(c0, 0, (size_t)Bsz * Hsz * 4, stream);
    hipMemsetAsync(c1, 0, (size_t)Bsz * Hsz * 4, stream);
    hipMemsetAsync(bufA0, 0, (size_t)Bsz * K1 * 2, stream);
    hipMemsetAsync(bufA1, 0, (size_t)Bsz * K1 * 2, stream);
    hipMemsetAsync(bufB0, 0, (size_t)Bsz * K2 * 2, stream);

    pack_cat<<<dim3(K1 / 32, NG / 64), 256, 0, stream>>>(Wenc1, eWhh0, 1024, eWih0, 32, K1);
    pack_cat<<<dim3(K2 / 32, NG / 64), 256, 0, stream>>>(Wenc2, eWih1, 1024, eWhh1, 1024, K2);
    pack_cat<<<dim3(K1 / 32, NG / 64), 256, 0, stream>>>(Wdec1a, dWhh0, 1024, dWih0, 32, K1);
    pack_cat<<<dim3(K2 / 32, NG / 64), 256, 0, stream>>>(Wdec1b, dWhh0, 1024, nullptr, 0, K2);
    pack_fold<<<dim3(NG / 16, 1024 / 128), 256, 0, stream>>>(Wdec1b, dWih0, linW);
    pack_cat<<<dim3(K2 / 32, NG / 64), 256, 0, stream>>>(Wdec2, dWih1, 1024, dWhh1, 1024, K2);
    pack_bias<<<(5 * NG + 255) / 256, 256, 0, stream>>>(bias5, eb0, eb1, db0, db1, dWih0, linb);
    pack_small<<<128, 256, 0, stream>>>(Wlin, bufA0, linW, in_seq);

    // ---- encoder ----
    for (int t = 0; t < Tsz; ++t) {
        int pp = t & 1;
        lstm_phase<K1><<<256, 256, 0, stream>>>(
            bufA[pp], Wenc1, be1, c0,
            bufB[pp], 0, bufA[1 - pp], 0, nullptr, 0,
            nullptr, nullptr);
        int tsel = (t + 1 < Tsz) ? t + 1 : Tsz - 1;
        lstm_phase<K2><<<256, 256, 0, stream>>>(
            bufB[pp], Wenc2, be2, c1,
            bufB[1 - pp], 1024, nullptr, 0, nullptr, 0,
            in_seq + (size_t)tsel * Fsz, bufA[1 - pp]);
    }

    // ---- decoder ----
    // t = 0: A = [h0_enc_final | x_last] (staged by enc kernels into bufA[0])
    lstm_phase<K1><<<256, 256, 0, stream>>>(
        bufA[0], Wdec1a, bd1a, c0,
        bufB[0], 0, bufD[1], 0, nullptr, 0,
        nullptr, nullptr);
    lstm_phase<K2><<<256, 256, 0, stream>>>(
        bufB[0], Wdec2, bd2, c1,
        bufB[1], 1024, bufD[1], 1024, H1hist, 0,
        nullptr, nullptr);
    for (int t = 1; t < Tsz; ++t) {
        int q = t & 1;
        lstm_phase<K2><<<256, 256, 0, stream>>>(
            bufD[q], Wdec1b, bd1b, c0,
            bufB[q], 0, bufD[1 - q], 0, nullptr, 0,
            nullptr, nullptr);
        lstm_phase<K2><<<256, 256, 0, stream>>>(
            bufB[q], Wdec2, bd2, c1,
            bufB[1 - q], 1024, bufD[1 - q], 1024, H1hist + (size_t)t * Bsz * Hsz, 0,
            nullptr, nullptr);
    }

    lin_out<<<512, 256, 0, stream>>>(H1hist, Wlin, linb, out);
}